// Round 19
// baseline (561.119 us; speedup 1.0000x reference)
//
#include <hip/hip_runtime.h>
#include <hip/hip_bf16.h>

#define NE   4096      // hyperedges
#define D1   512       // H1
#define D2   128       // H2
#define NNZV 131072    // nnz per incidence
#define MTOT 13312     // NA+NK+NV

typedef __attribute__((ext_vector_type(8))) short bf16x8;
typedef __attribute__((ext_vector_type(4))) float f32x4;

struct Params {
  const int*   rows[3]; const int* cols[3]; const float* vals[3];
  const float* Wn[3];  const float* bn[3];
  const float* Wzm[3]; const float* bzm[3];
  const float* Wzs[3]; const float* bzs[3];
  const float* We[3];  const float* be[3];
  const float* eps[3];
  const float* Watt; const float* batt; const float* uatt;
  const float* Wem;  const float* bem;  const float* Wes; const float* bes;
  const float* eps_e;
  int* cnt[6]; int* ptr[6]; int* cur[6]; int2* spair[6];
  __hip_bfloat16* Wbf[6];      // bf16 copies of gather sources (sub even: Wn[t], odd: We[t])
  __hip_bfloat16* hbf[3];      // node encoder output, bf16 [N_t][512]
  __hip_bfloat16* ebf[3];      // edge encoder output, bf16 [NE][512]
  __hip_bfloat16* eebf;        // attention-combined edge embed, bf16 [NE][512]
  __hip_bfloat16* Wzmt[3];     // Wzm^T bf16 [128][512]
  __hip_bfloat16* Wzst[3];     // Wzs^T bf16 [128][512]
  __hip_bfloat16* Wattt;       // Watt^T bf16 [256][512]
  __hip_bfloat16* Wemt;        // Wem^T bf16 [128][512]
  __hip_bfloat16* West;        // Wes^T bf16 [128][512]
  float* scores;               // [NE*3]
  __hip_bfloat16* Zbf; __hip_bfloat16* Zmbf; __hip_bfloat16* zebf; __hip_bfloat16* zembf;
  float* out;
  int rowbase[3];
  int n8pre[7];   // prefix sums of per-sub conv chunks (8 elems each)
  int ndw;        // dwords of counter region to zero
};

__device__ __forceinline__ float bf2f(short s) {
  return __uint_as_float((unsigned)(unsigned short)s << 16);
}
__device__ __forceinline__ short f2bf(float f) {
  return (short)__bfloat16_as_ushort(__float2bfloat16(f));
}

__device__ __forceinline__ int nseg_of(int sub) {
  if (sub & 1) return NE;
  int t = sub >> 1;
  return t == 0 ? 8192 : (t == 1 ? 4096 : 1024);
}

// round-14 prep: zero counters | Wn/We bf16 conv | Wzm/Wzs^T | Watt^T | Wem/Wes^T
__global__ void prep_kernel(Params p) {
  int i = blockIdx.x * blockDim.x + threadIdx.x;
  if (i < p.ndw) { ((int*)p.cnt[0])[i] = 0; return; }
  int c = i - p.ndw;
  if (c < p.n8pre[6]) {
    int s = 0;
#pragma unroll
    for (int k = 1; k < 6; ++k) if (c >= p.n8pre[k]) s = k;
    int off8 = c - p.n8pre[s];
    int t = s >> 1;
    const float* src = (s & 1) ? p.We[t] : p.Wn[t];
    __hip_bfloat16* dst = p.Wbf[s];
    const float4 a = *(const float4*)&src[(size_t)off8 * 8];
    const float4 b = *(const float4*)&src[(size_t)off8 * 8 + 4];
    bf16x8 o;
    o[0] = f2bf(a.x); o[1] = f2bf(a.y); o[2] = f2bf(a.z); o[3] = f2bf(a.w);
    o[4] = f2bf(b.x); o[5] = f2bf(b.y); o[6] = f2bf(b.z); o[7] = f2bf(b.w);
    *(bf16x8*)&dst[(size_t)off8 * 8] = o;
    return;
  }
  int cz = c - p.n8pre[6];
  if (cz < 6 * D1 * D2) {            // Wzm/Wzs transpose-conv
    int m = cz >> 16, e = cz & 65535;
    int t = m >> 1;
    const float* src = (m & 1) ? p.Wzs[t] : p.Wzm[t];
    __hip_bfloat16* dst = (m & 1) ? p.Wzst[t] : p.Wzmt[t];
    int k = e >> 7, n = e & 127;
    dst[n * D1 + k] = __float2bfloat16(src[e]);
    return;
  }
  int cz2 = cz - 6 * D1 * D2;
  if (cz2 < D1 * 256) {              // Watt^T
    int k = cz2 >> 8, n = cz2 & 255;
    p.Wattt[n * D1 + k] = __float2bfloat16(p.Watt[(size_t)k * 256 + n]);
    return;
  }
  int cz3 = cz2 - D1 * 256;
  if (cz3 < 2 * D1 * D2) {           // Wem/Wes^T
    int m = cz3 >> 16, e = cz3 & 65535;
    const float* src = m ? p.Wes : p.Wem;
    __hip_bfloat16* dst = m ? p.West : p.Wemt;
    int k = e >> 7, n = e & 127;
    dst[n * D1 + k] = __float2bfloat16(src[e]);
  }
}

__global__ void hist_kernel(Params p) {
  int i = blockIdx.x * blockDim.x + threadIdx.x;
  if (i >= 6 * NNZV) return;
  int sub = i >> 17, idx = i & (NNZV - 1);
  int type = sub >> 1, dir = sub & 1;
  int seg = dir ? p.cols[type][idx] : p.rows[type][idx];
  atomicAdd(&p.cnt[sub][seg], 1);
}

__global__ __launch_bounds__(1024) void scan_kernel(Params p) {
  int sub = blockIdx.x;
  int n = nseg_of(sub);
  const int* cnt = p.cnt[sub];
  int* ptr = p.ptr[sub];
  int* cur = p.cur[sub];
  __shared__ int lds[1024];
  int tid = threadIdx.x;
  int per = (n + 1023) >> 10;
  int base = tid * per;
  int s = 0;
  for (int q = 0; q < per; ++q) { int ix = base + q; if (ix < n) s += cnt[ix]; }
  lds[tid] = s;
  __syncthreads();
  for (int off = 1; off < 1024; off <<= 1) {
    int v = (tid >= off) ? lds[tid - off] : 0;
    __syncthreads();
    lds[tid] += v;
    __syncthreads();
  }
  int prefix = (tid == 0) ? 0 : lds[tid - 1];
  for (int q = 0; q < per; ++q) {
    int ix = base + q;
    if (ix < n) { int c = cnt[ix]; ptr[ix] = prefix; cur[ix] = prefix; prefix += c; }
  }
  if (tid == 1023) ptr[n] = lds[1023];
}

__global__ void scatter_kernel(Params p) {
  int i = blockIdx.x * blockDim.x + threadIdx.x;
  if (i >= 6 * NNZV) return;
  int sub = i >> 17, idx = i & (NNZV - 1);
  int type = sub >> 1, dir = sub & 1;
  int seg = dir ? p.cols[type][idx] : p.rows[type][idx];
  int oth = dir ? p.rows[type][idx] : p.cols[type][idx];
  int pos = atomicAdd(&p.cur[sub][seg], 1);
  p.spair[sub][pos] = make_int2(oth, __float_as_int(p.vals[type][idx]));
}

// one wave per output row; both dirs write bf16 (h for zmzs MFMA, e for scores MFMA).
__global__ __launch_bounds__(128) void spmm_kernel(Params p) {
  int g = blockIdx.x * 2 + (threadIdx.x >> 6);
  int sub, seg;
  if      (g <  8192) { sub = 0; seg = g;         }
  else if (g < 12288) { sub = 1; seg = g - 8192;  }
  else if (g < 16384) { sub = 2; seg = g - 12288; }
  else if (g < 20480) { sub = 3; seg = g - 16384; }
  else if (g < 21504) { sub = 4; seg = g - 20480; }
  else                { sub = 5; seg = g - 21504; }
  int type = sub >> 1, dir = sub & 1;
  const __hip_bfloat16* W = p.Wbf[sub];
  const float* bias = dir ? p.be[type] : p.bn[type];
  const int*  ptr  = p.ptr[sub];
  const int2* pair = p.spair[sub];
  int lane = threadIdx.x & 63;
  int c0 = lane * 8;
  float acc[8];
#pragma unroll
  for (int j = 0; j < 8; ++j) acc[j] = 0.f;
  int q0 = ptr[seg], q1 = ptr[seg + 1];
  int q = q0;
  for (; q + 4 <= q1; q += 4) {
    int2 pr0 = pair[q], pr1 = pair[q + 1], pr2 = pair[q + 2], pr3 = pair[q + 3];
    const bf16x8 w0 = *(const bf16x8*)(W + (size_t)pr0.x * D1 + c0);
    const bf16x8 w1 = *(const bf16x8*)(W + (size_t)pr1.x * D1 + c0);
    const bf16x8 w2 = *(const bf16x8*)(W + (size_t)pr2.x * D1 + c0);
    const bf16x8 w3 = *(const bf16x8*)(W + (size_t)pr3.x * D1 + c0);
    float v0 = __int_as_float(pr0.y), v1 = __int_as_float(pr1.y);
    float v2 = __int_as_float(pr2.y), v3 = __int_as_float(pr3.y);
#pragma unroll
    for (int j = 0; j < 8; ++j)
      acc[j] += v0 * bf2f(w0[j]) + v1 * bf2f(w1[j]) + v2 * bf2f(w2[j]) + v3 * bf2f(w3[j]);
  }
  for (; q < q1; ++q) {
    int2 pr = pair[q];
    const bf16x8 wv = *(const bf16x8*)(W + (size_t)pr.x * D1 + c0);
    float v = __int_as_float(pr.y);
#pragma unroll
    for (int j = 0; j < 8; ++j) acc[j] += v * bf2f(wv[j]);
  }
  const float4 b0 = *(const float4*)&bias[c0];
  const float4 b1 = *(const float4*)&bias[c0 + 4];
  float r[8];
  r[0] = tanhf(acc[0] + b0.x); r[1] = tanhf(acc[1] + b0.y);
  r[2] = tanhf(acc[2] + b0.z); r[3] = tanhf(acc[3] + b0.w);
  r[4] = tanhf(acc[4] + b1.x); r[5] = tanhf(acc[5] + b1.y);
  r[6] = tanhf(acc[6] + b1.z); r[7] = tanhf(acc[7] + b1.w);
  bf16x8 ob;
#pragma unroll
  for (int j = 0; j < 8; ++j) ob[j] = f2bf(r[j]);
  __hip_bfloat16* outp = dir ? p.ebf[type] : p.hbf[type];
  *(bf16x8*)&outp[(size_t)seg * D1 + c0] = ob;
}

// FUSED zmzs + scores (round-14 version).
__global__ __launch_bounds__(256) void zmzs_scores_kernel(Params p) {
  int b = blockIdx.x;
  int wid = threadIdx.x >> 6, lane = threadIdx.x & 63;
  int rloc = lane & 15, kg = lane >> 4;
  f32x4 zero = {0.f, 0.f, 0.f, 0.f};
  if (b < 208) {
    int type, blk;
    if      (b < 128) { type = 0; blk = b;       }
    else if (b < 192) { type = 1; blk = b - 128; }
    else              { type = 2; blk = b - 192; }
    int row0 = blk * 64 + wid * 16;
    const __hip_bfloat16* A  = p.hbf[type];
    const __hip_bfloat16* Bm = p.Wzmt[type];
    const __hip_bfloat16* Bs = p.Wzst[type];
    int mrow = row0 + rloc;
    f32x4 accm[8], accs[8];
#pragma unroll
    for (int nf = 0; nf < 8; ++nf) { accm[nf] = zero; accs[nf] = zero; }
    for (int kk = 0; kk < 16; ++kk) {
      bf16x8 a = *(const bf16x8*)(A + (size_t)mrow * D1 + kk * 32 + kg * 8);
#pragma unroll
      for (int nf = 0; nf < 8; ++nf) {
        int ncol = nf * 16 + rloc;
        bf16x8 bm = *(const bf16x8*)(Bm + (size_t)ncol * D1 + kk * 32 + kg * 8);
        accm[nf] = __builtin_amdgcn_mfma_f32_16x16x32_bf16(a, bm, accm[nf], 0, 0, 0);
        bf16x8 bs = *(const bf16x8*)(Bs + (size_t)ncol * D1 + kk * 32 + kg * 8);
        accs[nf] = __builtin_amdgcn_mfma_f32_16x16x32_bf16(a, bs, accs[nf], 0, 0, 0);
      }
    }
    int base = p.rowbase[type];
    const float* eps = p.eps[type];
    const float* bzm = p.bzm[type];
    const float* bzs = p.bzs[type];
    int rbase = row0 + kg * 4;
#pragma unroll
    for (int nf = 0; nf < 8; ++nf) {
      int col = nf * 16 + rloc;
      float bm = bzm[col], bs = bzs[col];
#pragma unroll
      for (int jj = 0; jj < 4; ++jj) {
        int row = rbase + jj;
        float zm = accm[nf][jj] + bm;
        float zs = accs[nf][jj] + bs;
        float ep = eps[(size_t)row * D2 + col];
        float z  = zm + ep * expf(zs);
        size_t oi = (size_t)(base + row) * D2 + col;
        p.Zmbf[oi] = __float2bfloat16(zm);
        p.Zbf[oi]  = __float2bfloat16(z);
      }
    }
  } else {
    int wtile = (b - 208) * 4 + wid;               // 0..767
    int t = wtile >> 8;
    int tile = wtile & 255;
    const __hip_bfloat16* A = p.ebf[t];
    const __hip_bfloat16* B = p.Wattt;
    int mrow = tile * 16 + rloc;
    f32x4 acc[16];
#pragma unroll
    for (int nf = 0; nf < 16; ++nf) acc[nf] = zero;
    for (int kk = 0; kk < 16; ++kk) {
      bf16x8 a = *(const bf16x8*)(A + (size_t)mrow * D1 + kk * 32 + kg * 8);
#pragma unroll
      for (int nf = 0; nf < 16; ++nf) {
        int ncol = nf * 16 + rloc;
        bf16x8 bv = *(const bf16x8*)(B + (size_t)ncol * D1 + kk * 32 + kg * 8);
        acc[nf] = __builtin_amdgcn_mfma_f32_16x16x32_bf16(a, bv, acc[nf], 0, 0, 0);
      }
    }
    float part[4] = {0.f, 0.f, 0.f, 0.f};
#pragma unroll
    for (int nf = 0; nf < 16; ++nf) {
      int col = nf * 16 + rloc;
      float ua = p.uatt[col], ba = p.batt[col];
#pragma unroll
      for (int jj = 0; jj < 4; ++jj)
        part[jj] += ua * tanhf(acc[nf][jj] + ba);
    }
#pragma unroll
    for (int off = 1; off < 16; off <<= 1) {
#pragma unroll
      for (int jj = 0; jj < 4; ++jj)
        part[jj] += __shfl_xor(part[jj], off, 64);
    }
    if (rloc == 0) {
#pragma unroll
      for (int jj = 0; jj < 4; ++jj) {
        int e = tile * 16 + kg * 4 + jj;
        p.scores[e * 3 + t] = part[jj];
      }
    }
  }
}

// softmax over 3 types + weighted bf16 merge -> eebf.  One wave per edge.
__global__ __launch_bounds__(256) void combine_kernel(Params p) {
  int e = blockIdx.x * 4 + (threadIdx.x >> 6);
  int lane = threadIdx.x & 63;
  float s0 = p.scores[e * 3 + 0];
  float s1 = p.scores[e * 3 + 1];
  float s2 = p.scores[e * 3 + 2];
  float m = fmaxf(s0, fmaxf(s1, s2));
  float a0 = expf(s0 - m), a1 = expf(s1 - m), a2 = expf(s2 - m);
  float inv = 1.f / (a0 + a1 + a2);
  a0 *= inv; a1 *= inv; a2 *= inv;
  int c0 = lane * 8;
  const bf16x8 va = *(const bf16x8*)(p.ebf[0] + (size_t)e * D1 + c0);
  const bf16x8 vk = *(const bf16x8*)(p.ebf[1] + (size_t)e * D1 + c0);
  const bf16x8 vv = *(const bf16x8*)(p.ebf[2] + (size_t)e * D1 + c0);
  bf16x8 o;
#pragma unroll
  for (int j = 0; j < 8; ++j) {
    float v = a0 * bf2f(va[j]) + a1 * bf2f(vk[j]) + a2 * bf2f(vv[j]);
    o[j] = f2bf(v);
  }
  *(bf16x8*)&p.eebf[(size_t)e * D1 + c0] = o;
}

// MFMA zem/zes (edges): N-split x2 (round-14 version).
__global__ __launch_bounds__(256) void zemzs_kernel(Params p) {
  int wid = threadIdx.x >> 6, lane = threadIdx.x & 63;
  int rloc = lane & 15, kg = lane >> 4;
  int row0 = blockIdx.x * 32 + (wid >> 1) * 16;
  int nh = wid & 1;
  const __hip_bfloat16* A  = p.eebf;
  const __hip_bfloat16* Bm = p.Wemt;
  const __hip_bfloat16* Bs = p.West;
  int mrow = row0 + rloc;
  f32x4 accm[4], accs[4];
  f32x4 zero = {0.f, 0.f, 0.f, 0.f};
#pragma unroll
  for (int nf = 0; nf < 4; ++nf) { accm[nf] = zero; accs[nf] = zero; }
  for (int kk = 0; kk < 16; ++kk) {
    bf16x8 a = *(const bf16x8*)(A + (size_t)mrow * D1 + kk * 32 + kg * 8);
#pragma unroll
    for (int nf = 0; nf < 4; ++nf) {
      int ncol = nh * 64 + nf * 16 + rloc;
      bf16x8 bm = *(const bf16x8*)(Bm + (size_t)ncol * D1 + kk * 32 + kg * 8);
      accm[nf] = __builtin_amdgcn_mfma_f32_16x16x32_bf16(a, bm, accm[nf], 0, 0, 0);
      bf16x8 bs = *(const bf16x8*)(Bs + (size_t)ncol * D1 + kk * 32 + kg * 8);
      accs[nf] = __builtin_amdgcn_mfma_f32_16x16x32_bf16(a, bs, accs[nf], 0, 0, 0);
    }
  }
  int rbase = row0 + kg * 4;
#pragma unroll
  for (int nf = 0; nf < 4; ++nf) {
    int col = nh * 64 + nf * 16 + rloc;
    float bm = p.bem[col], bs = p.bes[col];
#pragma unroll
    for (int jj = 0; jj < 4; ++jj) {
      int row = rbase + jj;
      float zm = accm[nf][jj] + bm;
      float zs = accs[nf][jj] + bs;
      float ep = p.eps_e[(size_t)row * D2 + col];
      float z  = zm + ep * expf(zs);
      size_t oi = (size_t)row * D2 + col;
      p.zembf[oi] = __float2bfloat16(zm);
      p.zebf[oi]  = __float2bfloat16(z);
    }
  }
}

// out[M,4096] = A[M,128] @ B[4096,128]^T, bf16 MFMA 16x16x32.
// Swapped-operand (transposed) tile -> direct row-contiguous f32x4 stores.
// SINGLE-VARIABLE CHANGE vs round 18: REGULAR stores (L2 write-back path,
// same as the 6.8 TB/s fill) instead of nontemporal. No LDS, no barrier.
#define DT_N 128
__global__ __launch_bounds__(256) void decode_kernel(Params p) {
  int which = blockIdx.z;
  const __hip_bfloat16* A = which ? p.Zmbf  : p.Zbf;
  const __hip_bfloat16* B = which ? p.zembf : p.zebf;
  float* C = p.out + (size_t)which * MTOT * NE;
  int n0 = blockIdx.x * DT_N;
  int m0 = blockIdx.y * 64;
  int wid  = threadIdx.x >> 6;
  int lane = threadIdx.x & 63;
  int rloc = lane & 15;
  int kg   = lane >> 4;
  int mrow = m0 + wid * 16 + rloc;
  bf16x8 a[4];
#pragma unroll
  for (int kk = 0; kk < 4; ++kk)
    a[kk] = *(const bf16x8*)(A + (size_t)mrow * D2 + kk * 32 + kg * 8);
  f32x4 zero = {0.f, 0.f, 0.f, 0.f};
  size_t rowbase = (size_t)mrow * NE;   // output row owned by this lane
#pragma unroll
  for (int nf = 0; nf < DT_N / 16; ++nf) {
    f32x4 acc = zero;
    int ncol = n0 + nf * 16 + rloc;
#pragma unroll
    for (int kk = 0; kk < 4; ++kk) {
      bf16x8 bv = *(const bf16x8*)(B + (size_t)ncol * D2 + kk * 32 + kg * 8);
      acc = __builtin_amdgcn_mfma_f32_16x16x32_bf16(bv, a[kk], acc, 0, 0, 0);
    }
    // transposed layout: acc[jj] = C[mrow][n0 + nf*16 + kg*4 + jj]
    *(f32x4*)&C[rowbase + n0 + nf * 16 + kg * 4] = acc;
  }
}

extern "C" void kernel_launch(void* const* d_in, const int* in_sizes, int n_in,
                              void* d_out, int out_size, void* d_ws, size_t ws_size,
                              hipStream_t stream) {
  (void)in_sizes; (void)n_in; (void)out_size; (void)ws_size;
  static const int Ns[3] = {8192, 4096, 1024};
  static const int NsegH[6] = {8192, 4096, 4096, 4096, 1024, 4096};

  Params p;
  for (int t = 0; t < 3; ++t) {
    const int o = t * 12;
    p.rows[t] = (const int*)d_in[o + 0];
    p.cols[t] = (const int*)d_in[o + 1];
    p.vals[t] = (const float*)d_in[o + 2];
    p.Wn[t]   = (const float*)d_in[o + 3];
    p.bn[t]   = (const float*)d_in[o + 4];
    p.Wzm[t]  = (const float*)d_in[o + 5];
    p.bzm[t]  = (const float*)d_in[o + 6];
    p.Wzs[t]  = (const float*)d_in[o + 7];
    p.bzs[t]  = (const float*)d_in[o + 8];
    p.We[t]   = (const float*)d_in[o + 9];
    p.be[t]   = (const float*)d_in[o + 10];
    p.eps[t]  = (const float*)d_in[o + 11];
  }
  p.Watt  = (const float*)d_in[36];
  p.batt  = (const float*)d_in[37];
  p.uatt  = (const float*)d_in[38];
  p.Wem   = (const float*)d_in[39];
  p.bem   = (const float*)d_in[40];
  p.Wes   = (const float*)d_in[41];
  p.bes   = (const float*)d_in[42];
  p.eps_e = (const float*)d_in[43];
  p.out = (float*)d_out;
  p.rowbase[0] = 0; p.rowbase[1] = 8192; p.rowbase[2] = 12288;

  char* ws = (char*)d_ws;
  size_t off = 0;
  auto alloc = [&](size_t bytes) -> char* {
    char* r = ws + off;
    off += (bytes + 255) & ~(size_t)255;
    return r;
  };
  for (int s = 0; s < 6; ++s) p.cnt[s] = (int*)alloc((size_t)(NsegH[s] + 1) * 4);
  size_t cnt_bytes = off;
  for (int s = 0; s < 6; ++s) {
    p.ptr[s]   = (int*)alloc((size_t)(NsegH[s] + 1) * 4);
    p.cur[s]   = (int*)alloc((size_t)(NsegH[s] + 1) * 4);
    p.spair[s] = (int2*)alloc((size_t)NNZV * 8);
  }
  for (int s = 0; s < 6; ++s) {
    int t = s >> 1;
    int nrows = (s & 1) ? Ns[t] : NE;
    p.Wbf[s] = (__hip_bfloat16*)alloc((size_t)nrows * D1 * 2);
  }
  for (int t = 0; t < 3; ++t) p.hbf[t]  = (__hip_bfloat16*)alloc((size_t)Ns[t] * D1 * 2);
  for (int t = 0; t < 3; ++t) p.ebf[t]  = (__hip_bfloat16*)alloc((size_t)NE * D1 * 2);
  p.eebf = (__hip_bfloat16*)alloc((size_t)NE * D1 * 2);
  for (int t = 0; t < 3; ++t) p.Wzmt[t] = (__hip_bfloat16*)alloc((size_t)D2 * D1 * 2);
  for (int t = 0; t < 3; ++t) p.Wzst[t] = (__hip_bfloat16*)alloc((size_t)D2 * D1 * 2);
  p.Wattt = (__hip_bfloat16*)alloc((size_t)256 * D1 * 2);
  p.Wemt  = (__hip_bfloat16*)alloc((size_t)D2 * D1 * 2);
  p.West  = (__hip_bfloat16*)alloc((size_t)D2 * D1 * 2);
  p.scores = (float*)alloc((size_t)NE * 3 * 4);
  p.Zbf    = (__hip_bfloat16*)alloc((size_t)MTOT * D2 * 2);
  p.Zmbf   = (__hip_bfloat16*)alloc((size_t)MTOT * D2 * 2);
  p.zebf   = (__hip_bfloat16*)alloc((size_t)NE * D2 * 2);
  p.zembf  = (__hip_bfloat16*)alloc((size_t)NE * D2 * 2);

  p.ndw = (int)(cnt_bytes >> 2);
  p.n8pre[0] = 0;
  for (int s = 0; s < 6; ++s) {
    int t = s >> 1;
    int nrows = (s & 1) ? Ns[t] : NE;
    p.n8pre[s + 1] = p.n8pre[s] + nrows * (D1 / 8);
  }

  int prep_threads = p.ndw + p.n8pre[6] + 6 * D1 * D2 + D1 * 256 + 2 * D1 * D2;
  prep_kernel       <<<(prep_threads + 255) / 256, 256, 0, stream>>>(p);
  hist_kernel       <<<(6 * NNZV + 255) / 256, 256, 0, stream>>>(p);
  scan_kernel       <<<6, 1024, 0, stream>>>(p);
  scatter_kernel    <<<(6 * NNZV + 255) / 256, 256, 0, stream>>>(p);
  spmm_kernel       <<<12800, 128, 0, stream>>>(p);
  zmzs_scores_kernel<<<400, 256, 0, stream>>>(p);
  combine_kernel    <<<1024, 256, 0, stream>>>(p);
  zemzs_kernel      <<<128, 256, 0, stream>>>(p);
  decode_kernel     <<<dim3(NE / DT_N, 208, 2), 256, 0, stream>>>(p);
}

// Round 20
// 540.026 us; speedup vs baseline: 1.0391x; 1.0391x over previous
//
#include <hip/hip_runtime.h>
#include <hip/hip_bf16.h>

#define NE   4096      // hyperedges
#define D1   512       // H1
#define D2   128       // H2
#define NNZV 131072    // nnz per incidence
#define MTOT 13312     // NA+NK+NV

typedef __attribute__((ext_vector_type(8))) short bf16x8;
typedef __attribute__((ext_vector_type(4))) float f32x4;

struct Params {
  const int*   rows[3]; const int* cols[3]; const float* vals[3];
  const float* Wn[3];  const float* bn[3];
  const float* Wzm[3]; const float* bzm[3];
  const float* Wzs[3]; const float* bzs[3];
  const float* We[3];  const float* be[3];
  const float* eps[3];
  const float* Watt; const float* batt; const float* uatt;
  const float* Wem;  const float* bem;  const float* Wes; const float* bes;
  const float* eps_e;
  int* cnt[6]; int* ptr[6]; int* cur[6]; int2* spair[6];
  __hip_bfloat16* Wbf[6];      // bf16 copies of gather sources (sub even: Wn[t], odd: We[t])
  __hip_bfloat16* hbf[3];      // node encoder output, bf16 [N_t][512]
  __hip_bfloat16* ebf[3];      // edge encoder output, bf16 [NE][512]
  __hip_bfloat16* eebf;        // attention-combined edge embed, bf16 [NE][512]
  __hip_bfloat16* Wzmt[3];     // Wzm^T bf16 [128][512]
  __hip_bfloat16* Wzst[3];     // Wzs^T bf16 [128][512]
  __hip_bfloat16* Wattt;       // Watt^T bf16 [256][512]
  __hip_bfloat16* Wemt;        // Wem^T bf16 [128][512]
  __hip_bfloat16* West;        // Wes^T bf16 [128][512]
  float* scores;               // [NE*3]
  __hip_bfloat16* Zbf; __hip_bfloat16* Zmbf; __hip_bfloat16* zebf; __hip_bfloat16* zembf;
  float* out;
  int rowbase[3];
  int n8pre[7];   // prefix sums of per-sub conv chunks (8 elems each)
  int ndw;        // dwords of counter region to zero
};

__device__ __forceinline__ float bf2f(short s) {
  return __uint_as_float((unsigned)(unsigned short)s << 16);
}
__device__ __forceinline__ short f2bf(float f) {
  return (short)__bfloat16_as_ushort(__float2bfloat16(f));
}

__device__ __forceinline__ int nseg_of(int sub) {
  if (sub & 1) return NE;
  int t = sub >> 1;
  return t == 0 ? 8192 : (t == 1 ? 4096 : 1024);
}

// prep: zero counters | Wn/We bf16 conv | Wzm/Wzs^T | Watt^T | Wem/Wes^T
__global__ void prep_kernel(Params p) {
  int i = blockIdx.x * blockDim.x + threadIdx.x;
  if (i < p.ndw) { ((int*)p.cnt[0])[i] = 0; return; }
  int c = i - p.ndw;
  if (c < p.n8pre[6]) {
    int s = 0;
#pragma unroll
    for (int k = 1; k < 6; ++k) if (c >= p.n8pre[k]) s = k;
    int off8 = c - p.n8pre[s];
    int t = s >> 1;
    const float* src = (s & 1) ? p.We[t] : p.Wn[t];
    __hip_bfloat16* dst = p.Wbf[s];
    const float4 a = *(const float4*)&src[(size_t)off8 * 8];
    const float4 b = *(const float4*)&src[(size_t)off8 * 8 + 4];
    bf16x8 o;
    o[0] = f2bf(a.x); o[1] = f2bf(a.y); o[2] = f2bf(a.z); o[3] = f2bf(a.w);
    o[4] = f2bf(b.x); o[5] = f2bf(b.y); o[6] = f2bf(b.z); o[7] = f2bf(b.w);
    *(bf16x8*)&dst[(size_t)off8 * 8] = o;
    return;
  }
  int cz = c - p.n8pre[6];
  if (cz < 6 * D1 * D2) {            // Wzm/Wzs transpose-conv
    int m = cz >> 16, e = cz & 65535;
    int t = m >> 1;
    const float* src = (m & 1) ? p.Wzs[t] : p.Wzm[t];
    __hip_bfloat16* dst = (m & 1) ? p.Wzst[t] : p.Wzmt[t];
    int k = e >> 7, n = e & 127;
    dst[n * D1 + k] = __float2bfloat16(src[e]);
    return;
  }
  int cz2 = cz - 6 * D1 * D2;
  if (cz2 < D1 * 256) {              // Watt^T
    int k = cz2 >> 8, n = cz2 & 255;
    p.Wattt[n * D1 + k] = __float2bfloat16(p.Watt[(size_t)k * 256 + n]);
    return;
  }
  int cz3 = cz2 - D1 * 256;
  if (cz3 < 2 * D1 * D2) {           // Wem/Wes^T
    int m = cz3 >> 16, e = cz3 & 65535;
    const float* src = m ? p.Wes : p.Wem;
    __hip_bfloat16* dst = m ? p.West : p.Wemt;
    int k = e >> 7, n = e & 127;
    dst[n * D1 + k] = __float2bfloat16(src[e]);
  }
}

__global__ void hist_kernel(Params p) {
  int i = blockIdx.x * blockDim.x + threadIdx.x;
  if (i >= 6 * NNZV) return;
  int sub = i >> 17, idx = i & (NNZV - 1);
  int type = sub >> 1, dir = sub & 1;
  int seg = dir ? p.cols[type][idx] : p.rows[type][idx];
  atomicAdd(&p.cnt[sub][seg], 1);
}

__global__ __launch_bounds__(1024) void scan_kernel(Params p) {
  int sub = blockIdx.x;
  int n = nseg_of(sub);
  const int* cnt = p.cnt[sub];
  int* ptr = p.ptr[sub];
  int* cur = p.cur[sub];
  __shared__ int lds[1024];
  int tid = threadIdx.x;
  int per = (n + 1023) >> 10;
  int base = tid * per;
  int s = 0;
  for (int q = 0; q < per; ++q) { int ix = base + q; if (ix < n) s += cnt[ix]; }
  lds[tid] = s;
  __syncthreads();
  for (int off = 1; off < 1024; off <<= 1) {
    int v = (tid >= off) ? lds[tid - off] : 0;
    __syncthreads();
    lds[tid] += v;
    __syncthreads();
  }
  int prefix = (tid == 0) ? 0 : lds[tid - 1];
  for (int q = 0; q < per; ++q) {
    int ix = base + q;
    if (ix < n) { int c = cnt[ix]; ptr[ix] = prefix; cur[ix] = prefix; prefix += c; }
  }
  if (tid == 1023) ptr[n] = lds[1023];
}

__global__ void scatter_kernel(Params p) {
  int i = blockIdx.x * blockDim.x + threadIdx.x;
  if (i >= 6 * NNZV) return;
  int sub = i >> 17, idx = i & (NNZV - 1);
  int type = sub >> 1, dir = sub & 1;
  int seg = dir ? p.cols[type][idx] : p.rows[type][idx];
  int oth = dir ? p.rows[type][idx] : p.cols[type][idx];
  int pos = atomicAdd(&p.cur[sub][seg], 1);
  p.spair[sub][pos] = make_int2(oth, __float_as_int(p.vals[type][idx]));
}

// one wave per output row; both dirs write bf16 (h for zmzs MFMA, e for scores MFMA).
__global__ __launch_bounds__(128) void spmm_kernel(Params p) {
  int g = blockIdx.x * 2 + (threadIdx.x >> 6);
  int sub, seg;
  if      (g <  8192) { sub = 0; seg = g;         }
  else if (g < 12288) { sub = 1; seg = g - 8192;  }
  else if (g < 16384) { sub = 2; seg = g - 12288; }
  else if (g < 20480) { sub = 3; seg = g - 16384; }
  else if (g < 21504) { sub = 4; seg = g - 20480; }
  else                { sub = 5; seg = g - 21504; }
  int type = sub >> 1, dir = sub & 1;
  const __hip_bfloat16* W = p.Wbf[sub];
  const float* bias = dir ? p.be[type] : p.bn[type];
  const int*  ptr  = p.ptr[sub];
  const int2* pair = p.spair[sub];
  int lane = threadIdx.x & 63;
  int c0 = lane * 8;
  float acc[8];
#pragma unroll
  for (int j = 0; j < 8; ++j) acc[j] = 0.f;
  int q0 = ptr[seg], q1 = ptr[seg + 1];
  int q = q0;
  for (; q + 4 <= q1; q += 4) {
    int2 pr0 = pair[q], pr1 = pair[q + 1], pr2 = pair[q + 2], pr3 = pair[q + 3];
    const bf16x8 w0 = *(const bf16x8*)(W + (size_t)pr0.x * D1 + c0);
    const bf16x8 w1 = *(const bf16x8*)(W + (size_t)pr1.x * D1 + c0);
    const bf16x8 w2 = *(const bf16x8*)(W + (size_t)pr2.x * D1 + c0);
    const bf16x8 w3 = *(const bf16x8*)(W + (size_t)pr3.x * D1 + c0);
    float v0 = __int_as_float(pr0.y), v1 = __int_as_float(pr1.y);
    float v2 = __int_as_float(pr2.y), v3 = __int_as_float(pr3.y);
#pragma unroll
    for (int j = 0; j < 8; ++j)
      acc[j] += v0 * bf2f(w0[j]) + v1 * bf2f(w1[j]) + v2 * bf2f(w2[j]) + v3 * bf2f(w3[j]);
  }
  for (; q < q1; ++q) {
    int2 pr = pair[q];
    const bf16x8 wv = *(const bf16x8*)(W + (size_t)pr.x * D1 + c0);
    float v = __int_as_float(pr.y);
#pragma unroll
    for (int j = 0; j < 8; ++j) acc[j] += v * bf2f(wv[j]);
  }
  const float4 b0 = *(const float4*)&bias[c0];
  const float4 b1 = *(const float4*)&bias[c0 + 4];
  float r[8];
  r[0] = tanhf(acc[0] + b0.x); r[1] = tanhf(acc[1] + b0.y);
  r[2] = tanhf(acc[2] + b0.z); r[3] = tanhf(acc[3] + b0.w);
  r[4] = tanhf(acc[4] + b1.x); r[5] = tanhf(acc[5] + b1.y);
  r[6] = tanhf(acc[6] + b1.z); r[7] = tanhf(acc[7] + b1.w);
  bf16x8 ob;
#pragma unroll
  for (int j = 0; j < 8; ++j) ob[j] = f2bf(r[j]);
  __hip_bfloat16* outp = dir ? p.ebf[type] : p.hbf[type];
  *(bf16x8*)&outp[(size_t)seg * D1 + c0] = ob;
}

// FUSED zmzs + scores.
__global__ __launch_bounds__(256) void zmzs_scores_kernel(Params p) {
  int b = blockIdx.x;
  int wid = threadIdx.x >> 6, lane = threadIdx.x & 63;
  int rloc = lane & 15, kg = lane >> 4;
  f32x4 zero = {0.f, 0.f, 0.f, 0.f};
  if (b < 208) {
    int type, blk;
    if      (b < 128) { type = 0; blk = b;       }
    else if (b < 192) { type = 1; blk = b - 128; }
    else              { type = 2; blk = b - 192; }
    int row0 = blk * 64 + wid * 16;
    const __hip_bfloat16* A  = p.hbf[type];
    const __hip_bfloat16* Bm = p.Wzmt[type];
    const __hip_bfloat16* Bs = p.Wzst[type];
    int mrow = row0 + rloc;
    f32x4 accm[8], accs[8];
#pragma unroll
    for (int nf = 0; nf < 8; ++nf) { accm[nf] = zero; accs[nf] = zero; }
    for (int kk = 0; kk < 16; ++kk) {
      bf16x8 a = *(const bf16x8*)(A + (size_t)mrow * D1 + kk * 32 + kg * 8);
#pragma unroll
      for (int nf = 0; nf < 8; ++nf) {
        int ncol = nf * 16 + rloc;
        bf16x8 bm = *(const bf16x8*)(Bm + (size_t)ncol * D1 + kk * 32 + kg * 8);
        accm[nf] = __builtin_amdgcn_mfma_f32_16x16x32_bf16(a, bm, accm[nf], 0, 0, 0);
        bf16x8 bs = *(const bf16x8*)(Bs + (size_t)ncol * D1 + kk * 32 + kg * 8);
        accs[nf] = __builtin_amdgcn_mfma_f32_16x16x32_bf16(a, bs, accs[nf], 0, 0, 0);
      }
    }
    int base = p.rowbase[type];
    const float* eps = p.eps[type];
    const float* bzm = p.bzm[type];
    const float* bzs = p.bzs[type];
    int rbase = row0 + kg * 4;
#pragma unroll
    for (int nf = 0; nf < 8; ++nf) {
      int col = nf * 16 + rloc;
      float bm = bzm[col], bs = bzs[col];
#pragma unroll
      for (int jj = 0; jj < 4; ++jj) {
        int row = rbase + jj;
        float zm = accm[nf][jj] + bm;
        float zs = accs[nf][jj] + bs;
        float ep = eps[(size_t)row * D2 + col];
        float z  = zm + ep * expf(zs);
        size_t oi = (size_t)(base + row) * D2 + col;
        p.Zmbf[oi] = __float2bfloat16(zm);
        p.Zbf[oi]  = __float2bfloat16(z);
      }
    }
  } else {
    int wtile = (b - 208) * 4 + wid;               // 0..767
    int t = wtile >> 8;
    int tile = wtile & 255;
    const __hip_bfloat16* A = p.ebf[t];
    const __hip_bfloat16* B = p.Wattt;
    int mrow = tile * 16 + rloc;
    f32x4 acc[16];
#pragma unroll
    for (int nf = 0; nf < 16; ++nf) acc[nf] = zero;
    for (int kk = 0; kk < 16; ++kk) {
      bf16x8 a = *(const bf16x8*)(A + (size_t)mrow * D1 + kk * 32 + kg * 8);
#pragma unroll
      for (int nf = 0; nf < 16; ++nf) {
        int ncol = nf * 16 + rloc;
        bf16x8 bv = *(const bf16x8*)(B + (size_t)ncol * D1 + kk * 32 + kg * 8);
        acc[nf] = __builtin_amdgcn_mfma_f32_16x16x32_bf16(a, bv, acc[nf], 0, 0, 0);
      }
    }
    float part[4] = {0.f, 0.f, 0.f, 0.f};
#pragma unroll
    for (int nf = 0; nf < 16; ++nf) {
      int col = nf * 16 + rloc;
      float ua = p.uatt[col], ba = p.batt[col];
#pragma unroll
      for (int jj = 0; jj < 4; ++jj)
        part[jj] += ua * tanhf(acc[nf][jj] + ba);
    }
#pragma unroll
    for (int off = 1; off < 16; off <<= 1) {
#pragma unroll
      for (int jj = 0; jj < 4; ++jj)
        part[jj] += __shfl_xor(part[jj], off, 64);
    }
    if (rloc == 0) {
#pragma unroll
      for (int jj = 0; jj < 4; ++jj) {
        int e = tile * 16 + kg * 4 + jj;
        p.scores[e * 3 + t] = part[jj];
      }
    }
  }
}

// softmax over 3 types + weighted bf16 merge -> eebf.  One wave per edge.
__global__ __launch_bounds__(256) void combine_kernel(Params p) {
  int e = blockIdx.x * 4 + (threadIdx.x >> 6);
  int lane = threadIdx.x & 63;
  float s0 = p.scores[e * 3 + 0];
  float s1 = p.scores[e * 3 + 1];
  float s2 = p.scores[e * 3 + 2];
  float m = fmaxf(s0, fmaxf(s1, s2));
  float a0 = expf(s0 - m), a1 = expf(s1 - m), a2 = expf(s2 - m);
  float inv = 1.f / (a0 + a1 + a2);
  a0 *= inv; a1 *= inv; a2 *= inv;
  int c0 = lane * 8;
  const bf16x8 va = *(const bf16x8*)(p.ebf[0] + (size_t)e * D1 + c0);
  const bf16x8 vk = *(const bf16x8*)(p.ebf[1] + (size_t)e * D1 + c0);
  const bf16x8 vv = *(const bf16x8*)(p.ebf[2] + (size_t)e * D1 + c0);
  bf16x8 o;
#pragma unroll
  for (int j = 0; j < 8; ++j) {
    float v = a0 * bf2f(va[j]) + a1 * bf2f(vk[j]) + a2 * bf2f(vv[j]);
    o[j] = f2bf(v);
  }
  *(bf16x8*)&p.eebf[(size_t)e * D1 + c0] = o;
}

// MFMA zem/zes (edges): N-split x2.
__global__ __launch_bounds__(256) void zemzs_kernel(Params p) {
  int wid = threadIdx.x >> 6, lane = threadIdx.x & 63;
  int rloc = lane & 15, kg = lane >> 4;
  int row0 = blockIdx.x * 32 + (wid >> 1) * 16;
  int nh = wid & 1;
  const __hip_bfloat16* A  = p.eebf;
  const __hip_bfloat16* Bm = p.Wemt;
  const __hip_bfloat16* Bs = p.West;
  int mrow = row0 + rloc;
  f32x4 accm[4], accs[4];
  f32x4 zero = {0.f, 0.f, 0.f, 0.f};
#pragma unroll
  for (int nf = 0; nf < 4; ++nf) { accm[nf] = zero; accs[nf] = zero; }
  for (int kk = 0; kk < 16; ++kk) {
    bf16x8 a = *(const bf16x8*)(A + (size_t)mrow * D1 + kk * 32 + kg * 8);
#pragma unroll
    for (int nf = 0; nf < 4; ++nf) {
      int ncol = nh * 64 + nf * 16 + rloc;
      bf16x8 bm = *(const bf16x8*)(Bm + (size_t)ncol * D1 + kk * 32 + kg * 8);
      accm[nf] = __builtin_amdgcn_mfma_f32_16x16x32_bf16(a, bm, accm[nf], 0, 0, 0);
      bf16x8 bs = *(const bf16x8*)(Bs + (size_t)ncol * D1 + kk * 32 + kg * 8);
      accs[nf] = __builtin_amdgcn_mfma_f32_16x16x32_bf16(a, bs, accs[nf], 0, 0, 0);
    }
  }
  int rbase = row0 + kg * 4;
#pragma unroll
  for (int nf = 0; nf < 4; ++nf) {
    int col = nh * 64 + nf * 16 + rloc;
    float bm = p.bem[col], bs = p.bes[col];
#pragma unroll
    for (int jj = 0; jj < 4; ++jj) {
      int row = rbase + jj;
      float zm = accm[nf][jj] + bm;
      float zs = accs[nf][jj] + bs;
      float ep = p.eps_e[(size_t)row * D2 + col];
      float z  = zm + ep * expf(zs);
      size_t oi = (size_t)row * D2 + col;
      p.zembf[oi] = __float2bfloat16(zm);
      p.zebf[oi]  = __float2bfloat16(z);
    }
  }
}

// out[M,4096] = A[M,128] @ B[4096,128]^T, bf16 MFMA 16x16x32.
// BEST MEASURED (round 18, 541us): swapped-operand transposed tile -> direct
// row-contiguous f32x4 NONTEMPORAL stores. No LDS, no barrier.
#define DT_N 128
__global__ __launch_bounds__(256) void decode_kernel(Params p) {
  int which = blockIdx.z;
  const __hip_bfloat16* A = which ? p.Zmbf  : p.Zbf;
  const __hip_bfloat16* B = which ? p.zembf : p.zebf;
  float* C = p.out + (size_t)which * MTOT * NE;
  int n0 = blockIdx.x * DT_N;
  int m0 = blockIdx.y * 64;
  int wid  = threadIdx.x >> 6;
  int lane = threadIdx.x & 63;
  int rloc = lane & 15;
  int kg   = lane >> 4;
  int mrow = m0 + wid * 16 + rloc;
  bf16x8 a[4];
#pragma unroll
  for (int kk = 0; kk < 4; ++kk)
    a[kk] = *(const bf16x8*)(A + (size_t)mrow * D2 + kk * 32 + kg * 8);
  f32x4 zero = {0.f, 0.f, 0.f, 0.f};
  size_t rowbase = (size_t)mrow * NE;   // output row owned by this lane
#pragma unroll
  for (int nf = 0; nf < DT_N / 16; ++nf) {
    f32x4 acc = zero;
    int ncol = n0 + nf * 16 + rloc;
#pragma unroll
    for (int kk = 0; kk < 4; ++kk) {
      bf16x8 bv = *(const bf16x8*)(B + (size_t)ncol * D2 + kk * 32 + kg * 8);
      acc = __builtin_amdgcn_mfma_f32_16x16x32_bf16(bv, a[kk], acc, 0, 0, 0);
    }
    // transposed layout: acc[jj] = C[mrow][n0 + nf*16 + kg*4 + jj]
    __builtin_nontemporal_store(acc,
      (f32x4*)&C[rowbase + n0 + nf * 16 + kg * 4]);
  }
}

extern "C" void kernel_launch(void* const* d_in, const int* in_sizes, int n_in,
                              void* d_out, int out_size, void* d_ws, size_t ws_size,
                              hipStream_t stream) {
  (void)in_sizes; (void)n_in; (void)out_size; (void)ws_size;
  static const int Ns[3] = {8192, 4096, 1024};
  static const int NsegH[6] = {8192, 4096, 4096, 4096, 1024, 4096};

  Params p;
  for (int t = 0; t < 3; ++t) {
    const int o = t * 12;
    p.rows[t] = (const int*)d_in[o + 0];
    p.cols[t] = (const int*)d_in[o + 1];
    p.vals[t] = (const float*)d_in[o + 2];
    p.Wn[t]   = (const float*)d_in[o + 3];
    p.bn[t]   = (const float*)d_in[o + 4];
    p.Wzm[t]  = (const float*)d_in[o + 5];
    p.bzm[t]  = (const float*)d_in[o + 6];
    p.Wzs[t]  = (const float*)d_in[o + 7];
    p.bzs[t]  = (const float*)d_in[o + 8];
    p.We[t]   = (const float*)d_in[o + 9];
    p.be[t]   = (const float*)d_in[o + 10];
    p.eps[t]  = (const float*)d_in[o + 11];
  }
  p.Watt  = (const float*)d_in[36];
  p.batt  = (const float*)d_in[37];
  p.uatt  = (const float*)d_in[38];
  p.Wem   = (const float*)d_in[39];
  p.bem   = (const float*)d_in[40];
  p.Wes   = (const float*)d_in[41];
  p.bes   = (const float*)d_in[42];
  p.eps_e = (const float*)d_in[43];
  p.out = (float*)d_out;
  p.rowbase[0] = 0; p.rowbase[1] = 8192; p.rowbase[2] = 12288;

  char* ws = (char*)d_ws;
  size_t off = 0;
  auto alloc = [&](size_t bytes) -> char* {
    char* r = ws + off;
    off += (bytes + 255) & ~(size_t)255;
    return r;
  };
  for (int s = 0; s < 6; ++s) p.cnt[s] = (int*)alloc((size_t)(NsegH[s] + 1) * 4);
  size_t cnt_bytes = off;
  for (int s = 0; s < 6; ++s) {
    p.ptr[s]   = (int*)alloc((size_t)(NsegH[s] + 1) * 4);
    p.cur[s]   = (int*)alloc((size_t)(NsegH[s] + 1) * 4);
    p.spair[s] = (int2*)alloc((size_t)NNZV * 8);
  }
  for (int s = 0; s < 6; ++s) {
    int t = s >> 1;
    int nrows = (s & 1) ? Ns[t] : NE;
    p.Wbf[s] = (__hip_bfloat16*)alloc((size_t)nrows * D1 * 2);
  }
  for (int t = 0; t < 3; ++t) p.hbf[t]  = (__hip_bfloat16*)alloc((size_t)Ns[t] * D1 * 2);
  for (int t = 0; t < 3; ++t) p.ebf[t]  = (__hip_bfloat16*)alloc((size_t)NE * D1 * 2);
  p.eebf = (__hip_bfloat16*)alloc((size_t)NE * D1 * 2);
  for (int t = 0; t < 3; ++t) p.Wzmt[t] = (__hip_bfloat16*)alloc((size_t)D2 * D1 * 2);
  for (int t = 0; t < 3; ++t) p.Wzst[t] = (__hip_bfloat16*)alloc((size_t)D2 * D1 * 2);
  p.Wattt = (__hip_bfloat16*)alloc((size_t)256 * D1 * 2);
  p.Wemt  = (__hip_bfloat16*)alloc((size_t)D2 * D1 * 2);
  p.West  = (__hip_bfloat16*)alloc((size_t)D2 * D1 * 2);
  p.scores = (float*)alloc((size_t)NE * 3 * 4);
  p.Zbf    = (__hip_bfloat16*)alloc((size_t)MTOT * D2 * 2);
  p.Zmbf   = (__hip_bfloat16*)alloc((size_t)MTOT * D2 * 2);
  p.zebf   = (__hip_bfloat16*)alloc((size_t)NE * D2 * 2);
  p.zembf  = (__hip_bfloat16*)alloc((size_t)NE * D2 * 2);

  p.ndw = (int)(cnt_bytes >> 2);
  p.n8pre[0] = 0;
  for (int s = 0; s < 6; ++s) {
    int t = s >> 1;
    int nrows = (s & 1) ? Ns[t] : NE;
    p.n8pre[s + 1] = p.n8pre[s] + nrows * (D1 / 8);
  }

  int prep_threads = p.ndw + p.n8pre[6] + 6 * D1 * D2 + D1 * 256 + 2 * D1 * D2;
  prep_kernel       <<<(prep_threads + 255) / 256, 256, 0, stream>>>(p);
  hist_kernel       <<<(6 * NNZV + 255) / 256, 256, 0, stream>>>(p);
  scan_kernel       <<<6, 1024, 0, stream>>>(p);
  scatter_kernel    <<<(6 * NNZV + 255) / 256, 256, 0, stream>>>(p);
  spmm_kernel       <<<12800, 128, 0, stream>>>(p);
  zmzs_scores_kernel<<<400, 256, 0, stream>>>(p);
  combine_kernel    <<<1024, 256, 0, stream>>>(p);
  zemzs_kernel      <<<128, 256, 0, stream>>>(p);
  decode_kernel     <<<dim3(NE / DT_N, 208, 2), 256, 0, stream>>>(p);
}